// Round 4
// baseline (234.245 us; speedup 1.0000x reference)
//
#include <hip/hip_runtime.h>

typedef unsigned short u16;
typedef unsigned int u32;
typedef __bf16 bf16x8 __attribute__((ext_vector_type(8)));
typedef u16 u16x8 __attribute__((ext_vector_type(8)));
typedef float floatx4 __attribute__((ext_vector_type(4)));

#define MFMA16(a, b, c) __builtin_amdgcn_mfma_f32_16x16x32_bf16((a), (b), (c), 0, 0, 0)

#define B_ 2
#define S0 4096
#define NH 16
#define HD 64
#define HID 1024
#define VSTR 216  // V^T LDS row stride (u16): odd*8 -> 2-way (free) b128 reads
#define PSTR 184  // P LDS row stride (u16): odd*8 -> 2-way free; keeps attn at 3 blk/CU

__device__ __forceinline__ float bf2f(u16 u) {
  union { u32 i; float f; } x; x.i = ((u32)u) << 16; return x.f;
}
__device__ __forceinline__ u16 f2bf(float f) {
  union { float f; u32 i; } x; x.f = f;
  u32 r = x.i + 0x7FFFu + ((x.i >> 16) & 1u);
  return (u16)(r >> 16);
}

__device__ __forceinline__ void glds16(const u16* g, u16* l) {
  __builtin_amdgcn_global_load_lds(
      (const __attribute__((address_space(1))) u32*)g,
      (__attribute__((address_space(3))) u32*)l, 16, 0, 0);
}

// -------- fused prep: convert X, convert mask+biases, transpose weights -----
__global__ __launch_bounds__(256) void prep(
    const float* __restrict__ X, const float* __restrict__ mask,
    const float* __restrict__ Wq, const float* __restrict__ bq,
    const float* __restrict__ Wk, const float* __restrict__ bk,
    const float* __restrict__ Wv, const float* __restrict__ bv,
    const float* __restrict__ Wo, const float* __restrict__ bo,
    u16* __restrict__ cX, u16* __restrict__ cmask, u16* __restrict__ cb,
    u16* __restrict__ WqkvT, u16* __restrict__ WoT) {
  __shared__ u16 tile[64][66];
  int bid = blockIdx.x;
  if (bid < 4096) {                       // ---- X fp32 -> bf16 (8 elem/thr)
    int i = (bid * 256 + threadIdx.x) * 8;
    u16x8 v;
#pragma unroll
    for (int j = 0; j < 8; j++) v[j] = f2bf(X[i + j]);
    *(u16x8*)(cX + i) = v;
  } else if (bid < 4144) {                // ---- mask + biases
    int tid = (bid - 4096) * 256 + threadIdx.x;
    if (tid < B_ * S0) {
      cmask[tid] = f2bf(mask[tid]);
    } else {
      int j = tid - B_ * S0;  // [0, 4096)
      int seg = j >> 10, idx = j & 1023;
      const float* src = (seg == 0) ? bq : (seg == 1) ? bk : (seg == 2) ? bv : bo;
      cb[seg * 1024 + idx] = f2bf(src[idx]);
    }
  } else {                                // ---- weight transpose (1024 blocks)
    int idx = bid - 4144;
    int mat = idx >> 8;
    const float* src = (mat == 0) ? Wq : (mat == 1) ? Wk : (mat == 2) ? Wv : Wo;
    u16* dst = (mat < 3) ? (WqkvT + (size_t)mat * HID * HID) : WoT;
    int t0 = ((idx >> 4) & 15) * 64;  // k base
    int c0 = (idx & 15) * 64;         // n base
    int tx = threadIdx.x & 63, ty = threadIdx.x >> 6;
#pragma unroll
    for (int i = 0; i < 16; i++) {
      int r = i * 4 + ty;
      tile[r][tx] = f2bf(src[(size_t)(t0 + r) * HID + c0 + tx]);
    }
    __syncthreads();
#pragma unroll
    for (int i = 0; i < 16; i++) {
      int r = i * 4 + ty;
      dst[(size_t)(c0 + r) * HID + t0 + tx] = tile[tx][r];
    }
  }
}

// ======================= QKV GEMM: 256x256 8-phase ==========================
// M=8192, N=3072, K=1024. 8 waves (2Mx4N), wave tile 128x64, BK=64, dbuf LDS
// 128 KiB. Per K-tile: 4 phases {ds_read | stage 1 unit | barrier | 16 MFMA |
// barrier}, ONE vmcnt(6) per tile (3 stage-units in flight across barriers).
// Unit rotation (free-time verified): P0 stages (T+1).A-odd-qtrs,
// P1 (T+2).A-even-qtrs, P2 (T+2).B-even-blks, P3 (T+2).B-odd-blks.
// B-n0 fragments are register-held P0->P3 so every LDS region is read in
// exactly one phase (enables the tight rotation above).
#define NTILE 16

#define STAGE_A(kt, half)                                                  \
  do {                                                                     \
    if ((kt) < NTILE) {                                                    \
      _Pragma("unroll") for (int i_ = 0; i_ < 2; i_++) {                   \
        int r0_ = (half) * 64 + i_ * 128 + wave * 8;                       \
        glds16(Ag + (size_t)r0_ * 1024 + (kt) * 64,                        \
               &sA[(kt) & 1][r0_ * 64]);                                   \
      }                                                                    \
    }                                                                      \
  } while (0)

#define STAGE_B(kt, odd)                                                   \
  do {                                                                     \
    if ((kt) < NTILE) {                                                    \
      _Pragma("unroll") for (int i_ = 0; i_ < 2; i_++) {                   \
        int g_ = wave * 16 + i_ * 8;                                       \
        int r0_ = (g_ >> 5) * 64 + (odd) * 32 + (g_ & 31);                 \
        glds16(Bg + (size_t)r0_ * 1024 + (kt) * 64,                        \
               &sB[(kt) & 1][r0_ * 64]);                                   \
      }                                                                    \
    }                                                                      \
  } while (0)

#define READ_A(mh)                                                         \
  do {                                                                     \
    _Pragma("unroll") for (int mi_ = 0; mi_ < 4; mi_++) {                  \
      int row_ = wm * 128 + (mh) * 64 + mi_ * 16 + l16;                    \
      af[mi_][0] = *(const bf16x8*)(&sA[bi][row_ * 64 + xk0]);             \
      af[mi_][1] = *(const bf16x8*)(&sA[bi][row_ * 64 + xk1]);             \
    }                                                                      \
  } while (0)

#define READ_B(arr, nh)                                                    \
  do {                                                                     \
    _Pragma("unroll") for (int ni_ = 0; ni_ < 2; ni_++) {                  \
      int row_ = wn * 64 + (nh) * 32 + ni_ * 16 + l16;                     \
      arr[ni_][0] = *(const bf16x8*)(&sB[bi][row_ * 64 + xk0]);            \
      arr[ni_][1] = *(const bf16x8*)(&sB[bi][row_ * 64 + xk1]);            \
    }                                                                      \
  } while (0)

#define PHASE_BAR1()                                                       \
  __builtin_amdgcn_sched_barrier(0);                                       \
  __builtin_amdgcn_s_barrier();                                            \
  asm volatile("s_waitcnt lgkmcnt(0)" ::: "memory");                       \
  __builtin_amdgcn_sched_barrier(0)

#define MFMA_PH(mh, nh, barr)                                              \
  do {                                                                     \
    __builtin_amdgcn_s_setprio(1);                                         \
    _Pragma("unroll") for (int ks_ = 0; ks_ < 2; ks_++)                    \
        _Pragma("unroll") for (int mi_ = 0; mi_ < 4; mi_++)                \
            _Pragma("unroll") for (int ni_ = 0; ni_ < 2; ni_++)            \
                acc[(mh) * 4 + mi_][(nh) * 2 + ni_] =                      \
        MFMA16(af[mi_][ks_], barr[ni_][ks_],                               \
               acc[(mh) * 4 + mi_][(nh) * 2 + ni_]);                       \
    __builtin_amdgcn_s_setprio(0);                                         \
    __builtin_amdgcn_sched_barrier(0);                                     \
    __builtin_amdgcn_s_barrier();                                          \
    __builtin_amdgcn_sched_barrier(0);                                     \
  } while (0)

__global__ __launch_bounds__(512, 2) void gemm_qkv_8ph(
    const u16* __restrict__ A, const u16* __restrict__ Bt,
    const u16* __restrict__ cb, u16* __restrict__ op) {
  __shared__ alignas(16) u16 sA[2][256 * 64];
  __shared__ alignas(16) u16 sB[2][256 * 64];
  int t = threadIdx.x;
  int wave = t >> 6, lane = t & 63;
  int quad = lane >> 4, l16 = lane & 15;
  int wm = wave >> 2, wn = wave & 3;
  int tile_m = blockIdx.x * 256;
  int tile_n = blockIdx.y * 256;

  floatx4 acc[8][4] = {};
  bf16x8 af[4][2], bn0[2][2], bn1[2][2];

  // staging pointers (pre-swizzled global source, linear LDS dest)
  int srow = lane >> 3;
  int scol = ((lane & 7) ^ srow) * 8;
  const u16* Ag = A + (size_t)(tile_m + srow) * 1024 + scol;
  const u16* Bg = Bt + (size_t)(tile_n + srow) * 1024 + scol;

  // fragment chunk offsets (un-swizzle on read)
  int xk0 = (quad ^ (l16 & 7)) * 8;
  int xk1 = ((4 + quad) ^ (l16 & 7)) * 8;

  // ---- prologue: tile0 fully + tile1 U0,U1,U2 (14 loads), keep 6 in flight
  STAGE_A(0, 0);
  STAGE_B(0, 0);
  STAGE_B(0, 1);
  STAGE_A(0, 1);
  STAGE_A(1, 0);
  STAGE_B(1, 0);
  STAGE_B(1, 1);
  asm volatile("s_waitcnt vmcnt(6)" ::: "memory");
  __builtin_amdgcn_s_barrier();
  __builtin_amdgcn_sched_barrier(0);

  for (int T = 0; T < NTILE; ++T) {
    int bi = T & 1;
    // ---- P0: A-m0 + B-n0 reads; stage (T+1) A-odd-quarters
    READ_A(0);
    READ_B(bn0, 0);
    STAGE_A(T + 1, 1);
    PHASE_BAR1();
    MFMA_PH(0, 0, bn0);
    // ---- P1: B-n1 reads; stage (T+2) A-even-quarters
    READ_B(bn1, 1);
    STAGE_A(T + 2, 0);
    PHASE_BAR1();
    MFMA_PH(0, 1, bn1);
    // ---- P2: A-m1 reads; stage (T+2) B-even-blocks
    READ_A(1);
    STAGE_B(T + 2, 0);
    PHASE_BAR1();
    MFMA_PH(1, 1, bn1);
    // ---- P3: no reads; stage (T+2) B-odd-blocks; counted vmcnt
    STAGE_B(T + 2, 1);
    if (T < NTILE - 2) {
      asm volatile("s_waitcnt vmcnt(6)" ::: "memory");
    } else {
      asm volatile("s_waitcnt vmcnt(0)" ::: "memory");
    }
    PHASE_BAR1();
    MFMA_PH(1, 0, bn0);
  }

  // ---- epilogue: scatter to Q/K/V [3][B][H][S][D] bf16 with bias ----------
#pragma unroll
  for (int mf = 0; mf < 8; mf++) {
    int row0 = tile_m + wm * 128 + mf * 16 + quad * 4;
    int bb = row0 >> 12;
    int sbase = row0 & (S0 - 1);
#pragma unroll
    for (int nf = 0; nf < 4; nf++) {
      int col = tile_n + wn * 64 + nf * 16 + l16;
      int p = col >> 10;
      int rem = col & 1023;
      float bias = bf2f(cb[p * 1024 + rem]);
      int hh = rem >> 6, dd = rem & 63;
      u16* dp = op + ((size_t)(((p * 2 + bb) * NH + hh)) * S0 + sbase) * HD + dd;
#pragma unroll
      for (int r = 0; r < 4; r++)
        dp[(size_t)r * HD] = f2bf(acc[mf][nf][r] + bias);
    }
  }
}

// ---------------- bf16 GEMM (out-proj): C = A * Bt^T + bias, fp32 out ------
__global__ __launch_bounds__(256) void gemm_bf16_tn(
    const u16* __restrict__ A, const u16* __restrict__ Bt,
    const u16* __restrict__ cb, float* __restrict__ op, int K) {
  constexpr int BN = 128;
  constexpr int NT = BN / 32;
  __shared__ alignas(16) u16 sA[128 * 64];
  __shared__ alignas(16) u16 sB[BN * 64];
  int t = threadIdx.x;
  int wave = t >> 6, lane = t & 63;
  int wm = wave >> 1, wn = wave & 1;
  int quad = lane >> 4, l16 = lane & 15;
  int tile_m = blockIdx.x * 128;
  int tile_n = blockIdx.y * BN;

  floatx4 acc[4][NT] = {};

  int row_l = lane >> 3;
  int col_l = ((lane & 7) ^ row_l) * 8;
  const u16* Ag = A + (size_t)(tile_m + wave * 8 + row_l) * K + col_l;
  const u16* Bg = Bt + (size_t)(tile_n + wave * 8 + row_l) * K + col_l;
  u16* lA = sA + wave * 8 * 64;
  u16* lB = sB + wave * 8 * 64;

  for (int k0 = 0; k0 < K; k0 += 64) {
    __syncthreads();
#pragma unroll
    for (int r = 0; r < 4; r++)
      glds16(Ag + (size_t)(r * 32) * K + k0, lA + r * 2048);
#pragma unroll
    for (int r = 0; r < BN / 32; r++)
      glds16(Bg + (size_t)(r * 32) * K + k0, lB + r * 2048);
    __syncthreads();

#pragma unroll
    for (int ks = 0; ks < 2; ks++) {
      bf16x8 af[4], bfr[NT];
#pragma unroll
      for (int mt = 0; mt < 4; mt++) {
        int row = wm * 64 + mt * 16 + l16;
        int p = (ks * 4 + quad) ^ (row & 7);
        af[mt] = *(const bf16x8*)(sA + row * 64 + p * 8);
      }
#pragma unroll
      for (int nt = 0; nt < NT; nt++) {
        int row = wn * (BN / 2) + nt * 16 + l16;
        int p = (ks * 4 + quad) ^ (row & 7);
        bfr[nt] = *(const bf16x8*)(sB + row * 64 + p * 8);
      }
#pragma unroll
      for (int mt = 0; mt < 4; mt++)
#pragma unroll
        for (int nt = 0; nt < NT; nt++)
          acc[mt][nt] = MFMA16(af[mt], bfr[nt], acc[mt][nt]);
    }
  }

#pragma unroll
  for (int mt = 0; mt < 4; mt++) {
    int row0 = tile_m + wm * 64 + mt * 16 + quad * 4;
#pragma unroll
    for (int nt = 0; nt < NT; nt++) {
      int col = tile_n + wn * (BN / 2) + nt * 16 + l16;
      float bias = bf2f(cb[3 * 1024 + col]);
      float* dp = op + (size_t)row0 * HID + col;
#pragma unroll
      for (int r = 0; r < 4; r++)
        dp[(size_t)r * HID] = acc[mt][nt][r] + bias;  // fp32 output
    }
  }
}

// ---------------- windowed attention: one block per (b, h, chunk) ----------
// Wave w covers queries [w*16, w*16+16) and keys [w*16, w*16+144) rel kbase
// (exactly the band). K staged in LDS (XOR-swizzled); same buffer re-staged
// as V^T (stride VSTR -> conflict-free PV ds_read_b128); V global loads
// issued before softmax to hide latency; Q hoisted above the first barrier.
// LDS 51.6 KB -> 3 blocks/CU (PSTR=184 keeps us under the 53.3 KB cliff).
__global__ __launch_bounds__(256) void attn_win(
    const u16* __restrict__ Q, const u16* __restrict__ Kp,
    const u16* __restrict__ Vp, const u16* __restrict__ cmask,
    u16* __restrict__ ctx) {
  __shared__ alignas(16) u16 buf0[64 * VSTR];   // phase1: K swizzled [slot][64]
                                                // phase2: V^T [d][VSTR]
  __shared__ alignas(16) u16 sP[4 * 16 * PSTR]; // [wave][qrow][key 0..160)
  __shared__ u16 sMk[208];

  int bid = blockIdx.x;
  int c = bid & 63;
  int h = (bid >> 6) & 15;
  int b = bid >> 10;
  int t = threadIdx.x;
  int wave = t >> 6, lane = t & 63;
  int quad = lane >> 4, l16 = lane & 15;
  int koff = wave * 16;  // this wave's key-window start (rel kbase)

  const u16* Qb = Q + (size_t)(b * NH + h) * S0 * HD;
  const u16* Kb = Kp + (size_t)(b * NH + h) * S0 * HD;
  const u16* Vb = Vp + (size_t)(b * NH + h) * S0 * HD;
  int kbase = (c - 1) * 64;  // global key index of slot 0

  // ---- stage K via glds16, source-swizzled (chunk csrc -> LDS chunk l&7) --
  int rrow = lane >> 3;                 // row within the wave's 8-row group
  int csrc = ((lane & 7) ^ rrow) * 8;   // swizzled source chunk (elems)
#pragma unroll
  for (int p = 0; p < 7; p++) {
    int sl0 = p * 32 + wave * 8;        // wave-uniform row base (mult of 8)
    if (sl0 < 208) {
      int key = kbase + sl0 + rrow;
      int kc = key < 0 ? 0 : (key > S0 - 1 ? S0 - 1 : key);
      glds16(Kb + (size_t)kc * HD + csrc, buf0 + sl0 * 64);
    }
  }
  if (t < 208) {
    int j = kbase + t;
    sMk[t] = (j >= 0 && j < S0) ? cmask[(size_t)b * S0 + j] : (u16)0;
  }

  // ---- hoist Q fragments: global-load latency overlaps the K-stage drain --
  int qrow = c * 64 + wave * 16 + l16;
  bf16x8 aqv[2];
#pragma unroll
  for (int ks = 0; ks < 2; ks++)
    aqv[ks] = *(const bf16x8*)(Qb + (size_t)qrow * HD + ks * 32 + quad * 8);

  __syncthreads();

  // ---- QK from LDS: 9 key tiles cover the band exactly --------------------
  floatx4 sc[9] = {};
  __builtin_amdgcn_s_setprio(1);
#pragma unroll
  for (int ks = 0; ks < 2; ks++) {
#pragma unroll
    for (int nt = 0; nt < 9; nt++) {
      int slot = koff + nt * 16 + l16;
      int pch = ((ks * 4 + quad) ^ (l16 & 7)) * 8;  // un-swizzle
      bf16x8 bk = *(const bf16x8*)(buf0 + slot * 64 + pch);
      sc[nt] = MFMA16(aqv[ks], bk, sc[nt]);
    }
  }
  __builtin_amdgcn_s_setprio(0);

  // ---- preload V into registers (latency hides under softmax) -------------
  u16x8 vreg[7];
#pragma unroll
  for (int i = 0; i < 7; i++) {
    int e = i * 256 + t;  // 208*8 = 1664 tasks
    if (e < 1664) {
      int dg = e / 208;         // d block of 8
      int slot = e - dg * 208;  // 0..207
      int key = kbase + slot;
      int kc = key < 0 ? 0 : (key > S0 - 1 ? S0 - 1 : key);
      vreg[i] = *(const u16x8*)(Vb + (size_t)kc * HD + dg * 8);
    }
  }

  // ---- mask + softmax (rows across the 16 lanes of a quad) + write P ------
  int qrel_base = wave * 16 + quad * 4;
  u16* myP = sP + wave * 16 * PSTR;
  float kmask[9];
#pragma unroll
  for (int nt = 0; nt < 9; nt++) kmask[nt] = bf2f(sMk[koff + nt * 16 + l16]);

#pragma unroll
  for (int reg = 0; reg < 4; reg++) {
    int qrel = qrel_base + reg;
    float v[9];
    float m = -3e38f;
#pragma unroll
    for (int nt = 0; nt < 9; nt++) {
      int slot = koff + nt * 16 + l16;  // band: qrel <= slot <= qrel+128
      bool ok = (slot >= qrel) && (slot <= qrel + 128) && (kmask[nt] > 0.f);
      float s = ok ? sc[nt][reg] * 0.125f : -1e30f;
      v[nt] = s;
      m = fmaxf(m, s);
    }
#pragma unroll
    for (int off = 1; off <= 8; off <<= 1) m = fmaxf(m, __shfl_xor(m, off));
    float sum = 0.f;
#pragma unroll
    for (int nt = 0; nt < 9; nt++) {
      float p = __expf(v[nt] - m);
      v[nt] = p;
      sum += p;
    }
#pragma unroll
    for (int off = 1; off <= 8; off <<= 1) sum += __shfl_xor(sum, off);
    float inv = 1.0f / sum;
    int prow = (quad * 4 + reg) * PSTR;
#pragma unroll
    for (int nt = 0; nt < 9; nt++)
      myP[prow + nt * 16 + l16] = f2bf(v[nt] * inv);
    myP[prow + 144 + l16] = 0;  // zero-pad tile 9 -> P width 160
  }
  __syncthreads();  // all waves done reading K from buf0

  // ---- scatter V^T into buf0 ([d][key], stride VSTR) ----------------------
#pragma unroll
  for (int i = 0; i < 7; i++) {
    int e = i * 256 + t;
    if (e < 1664) {
      int dg = e / 208;
      int slot = e - dg * 208;
#pragma unroll
      for (int j = 0; j < 8; j++) buf0[(dg * 8 + j) * VSTR + slot] = vreg[i][j];
    }
  }
  __syncthreads();

  // ---- PV over the 160-key padded window ----------------------------------
  floatx4 oc[4] = {};
  __builtin_amdgcn_s_setprio(1);
#pragma unroll
  for (int ks = 0; ks < 5; ks++) {
    bf16x8 ap = *(const bf16x8*)(myP + l16 * PSTR + ks * 32 + quad * 8);
#pragma unroll
    for (int nt = 0; nt < 4; nt++) {
      bf16x8 bv =
          *(const bf16x8*)(buf0 + (nt * 16 + l16) * VSTR + koff + ks * 32 + quad * 8);
      oc[nt] = MFMA16(ap, bv, oc[nt]);
    }
  }
  __builtin_amdgcn_s_setprio(0);

  int srow = c * 64 + wave * 16 + quad * 4;
#pragma unroll
  for (int nt = 0; nt < 4; nt++) {
    u16* dp = ctx + (size_t)(b * S0 + srow) * HID + h * HD + nt * 16 + l16;
#pragma unroll
    for (int reg = 0; reg < 4; reg++)
      dp[(size_t)reg * HID] = f2bf(oc[nt][reg]);
  }
}

// ---------------------------------------------------------------------------
extern "C" void kernel_launch(void* const* d_in, const int* in_sizes, int n_in,
                              void* d_out, int out_size, void* d_ws, size_t ws_size,
                              hipStream_t stream) {
  const float* X = (const float*)d_in[0];
  const float* mask = (const float*)d_in[1];
  const float* Wq = (const float*)d_in[2];
  const float* bq = (const float*)d_in[3];
  const float* Wk = (const float*)d_in[4];
  const float* bk = (const float*)d_in[5];
  const float* Wv = (const float*)d_in[6];
  const float* bv = (const float*)d_in[7];
  const float* Wo = (const float*)d_in[8];
  const float* bo = (const float*)d_in[9];
  char* ws = (char*)d_ws;

  const size_t MB = 1048576;
  u16* cmask = (u16*)(ws + 256);               // 16 KB
  u16* cb = (u16*)(ws + 256 + 16384);          // 8 KB
  u16* cX = (u16*)(ws + 1 * MB);               // 16 MB (CTX aliases after gemm0)
  u16* WqkvT = (u16*)(ws + 17 * MB);           // 6 MB
  u16* WoT = (u16*)(ws + 23 * MB);             // 2 MB
  u16* QKV = (u16*)(ws + 25 * MB);             // 48 MB
  u16* CTX = cX;                               // alias: cX dead after gemm0

  const size_t per_qkv = (size_t)B_ * NH * S0 * HD;  // elements per Q/K/V

  prep<<<4096 + 48 + 1024, 256, 0, stream>>>(X, mask, Wq, bq, Wk, bk, Wv, bv,
                                             Wo, bo, cX, cmask, cb, WqkvT, WoT);
  gemm_qkv_8ph<<<dim3(32, 12), 512, 0, stream>>>(cX, WqkvT, cb, QKV);
  attn_win<<<dim3(B_ * NH * 64), 256, 0, stream>>>(QKV, QKV + per_qkv,
                                                   QKV + 2 * per_qkv, cmask, CTX);
  gemm_bf16_tn<<<dim3(64, 8), 256, 0, stream>>>(CTX, WoT, cb, (float*)d_out, HID);
}

// Round 5
// 225.219 us; speedup vs baseline: 1.0401x; 1.0401x over previous
//
#include <hip/hip_runtime.h>

typedef unsigned short u16;
typedef unsigned int u32;
typedef __bf16 bf16x8 __attribute__((ext_vector_type(8)));
typedef u16 u16x8 __attribute__((ext_vector_type(8)));
typedef float floatx4 __attribute__((ext_vector_type(4)));

#define MFMA16(a, b, c) __builtin_amdgcn_mfma_f32_16x16x32_bf16((a), (b), (c), 0, 0, 0)

#define B_ 2
#define S0 4096
#define NH 16
#define HD 64
#define HID 1024
#define VSTR 216  // V^T LDS row stride (u16): odd*8 -> 2-way (free) b128 reads
#define PSTR 184  // P LDS row stride (u16): odd*8 -> 2-way free; attn stays 3 blk/CU

__device__ __forceinline__ float bf2f(u16 u) {
  union { u32 i; float f; } x; x.i = ((u32)u) << 16; return x.f;
}
__device__ __forceinline__ u16 f2bf(float f) {
  union { float f; u32 i; } x; x.f = f;
  u32 r = x.i + 0x7FFFu + ((x.i >> 16) & 1u);
  return (u16)(r >> 16);
}

__device__ __forceinline__ void glds16(const u16* g, u16* l) {
  __builtin_amdgcn_global_load_lds(
      (const __attribute__((address_space(1))) u32*)g,
      (__attribute__((address_space(3))) u32*)l, 16, 0, 0);
}

// -------- fused prep: convert X, convert mask+biases, transpose weights -----
__global__ __launch_bounds__(256) void prep(
    const float* __restrict__ X, const float* __restrict__ mask,
    const float* __restrict__ Wq, const float* __restrict__ bq,
    const float* __restrict__ Wk, const float* __restrict__ bk,
    const float* __restrict__ Wv, const float* __restrict__ bv,
    const float* __restrict__ Wo, const float* __restrict__ bo,
    u16* __restrict__ cX, u16* __restrict__ cmask, u16* __restrict__ cb,
    u16* __restrict__ WqkvT, u16* __restrict__ WoT) {
  __shared__ u16 tile[64][66];
  int bid = blockIdx.x;
  if (bid < 4096) {                       // ---- X fp32 -> bf16 (8 elem/thr)
    int i = (bid * 256 + threadIdx.x) * 8;
    const float4* Xv = (const float4*)(X + i);
    float4 a = Xv[0], b = Xv[1];
    u16x8 v;
    v[0] = f2bf(a.x); v[1] = f2bf(a.y); v[2] = f2bf(a.z); v[3] = f2bf(a.w);
    v[4] = f2bf(b.x); v[5] = f2bf(b.y); v[6] = f2bf(b.z); v[7] = f2bf(b.w);
    *(u16x8*)(cX + i) = v;
  } else if (bid < 4144) {                // ---- mask + biases
    int tid = (bid - 4096) * 256 + threadIdx.x;
    if (tid < B_ * S0) {
      cmask[tid] = f2bf(mask[tid]);
    } else {
      int j = tid - B_ * S0;  // [0, 4096)
      int seg = j >> 10, idx = j & 1023;
      const float* src = (seg == 0) ? bq : (seg == 1) ? bk : (seg == 2) ? bv : bo;
      cb[seg * 1024 + idx] = f2bf(src[idx]);
    }
  } else {                                // ---- weight transpose (1024 blocks)
    int idx = bid - 4144;
    int mat = idx >> 8;
    const float* src = (mat == 0) ? Wq : (mat == 1) ? Wk : (mat == 2) ? Wv : Wo;
    u16* dst = (mat < 3) ? (WqkvT + (size_t)mat * HID * HID) : WoT;
    int t0 = ((idx >> 4) & 15) * 64;  // k base
    int c0 = (idx & 15) * 64;         // n base
    int tx = threadIdx.x & 63, ty = threadIdx.x >> 6;
#pragma unroll
    for (int i = 0; i < 16; i++) {
      int r = i * 4 + ty;
      tile[r][tx] = f2bf(src[(size_t)(t0 + r) * HID + c0 + tx]);
    }
    __syncthreads();
#pragma unroll
    for (int i = 0; i < 16; i++) {
      int r = i * 4 + ty;
      dst[(size_t)(c0 + r) * HID + t0 + tx] = tile[tx][r];
    }
  }
}

// ---------------- bf16 GEMM: C[m][n] = A[m][k] * Bt[n][k] + bias -----------
// BK=64, glds16 staging, 16B-chunk XOR swizzle -> conflict-free ds_read_b128.
// 2-phase proven structure (28KB/32KB LDS -> 5 blk/CU). Grid is N-MAJOR
// (x = n-tile, y = m-tile): per-XCD the 4 B-panels (0.75MB) stay L2-hot
// forever while A streams once -> lower refetch/drain latency than m-major.
template <int BN, int MODE>
__global__ __launch_bounds__(256) void gemm_bf16_tn(
    const u16* __restrict__ A, const u16* __restrict__ Bt,
    const u16* __restrict__ cb, void* __restrict__ outp, int K) {
  constexpr int NT = BN / 32;  // 16-col tiles per wave (wave covers BN/2 cols)
  __shared__ alignas(16) u16 sA[128 * 64];
  __shared__ alignas(16) u16 sB[BN * 64];
  int t = threadIdx.x;
  int wave = t >> 6, lane = t & 63;
  int wm = wave >> 1, wn = wave & 1;
  int quad = lane >> 4, l16 = lane & 15;
  int tile_m = blockIdx.y * 128;   // n-major launch: y = M
  int tile_n = blockIdx.x * BN;    //                 x = N

  floatx4 acc[4][NT] = {};

  int row_l = lane >> 3;
  int col_l = ((lane & 7) ^ row_l) * 8;
  const u16* Ag = A + (size_t)(tile_m + wave * 8 + row_l) * K + col_l;
  const u16* Bg = Bt + (size_t)(tile_n + wave * 8 + row_l) * K + col_l;
  u16* lA = sA + wave * 8 * 64;
  u16* lB = sB + wave * 8 * 64;

  for (int k0 = 0; k0 < K; k0 += 64) {
    __syncthreads();
#pragma unroll
    for (int r = 0; r < 4; r++)
      glds16(Ag + (size_t)(r * 32) * K + k0, lA + r * 2048);
#pragma unroll
    for (int r = 0; r < BN / 32; r++)
      glds16(Bg + (size_t)(r * 32) * K + k0, lB + r * 2048);
    __syncthreads();

#pragma unroll
    for (int ks = 0; ks < 2; ks++) {
      bf16x8 af[4], bfr[NT];
#pragma unroll
      for (int mt = 0; mt < 4; mt++) {
        int row = wm * 64 + mt * 16 + l16;
        int p = (ks * 4 + quad) ^ (row & 7);
        af[mt] = *(const bf16x8*)(sA + row * 64 + p * 8);
      }
#pragma unroll
      for (int nt = 0; nt < NT; nt++) {
        int row = wn * (BN / 2) + nt * 16 + l16;
        int p = (ks * 4 + quad) ^ (row & 7);
        bfr[nt] = *(const bf16x8*)(sB + row * 64 + p * 8);
      }
#pragma unroll
      for (int mt = 0; mt < 4; mt++)
#pragma unroll
        for (int nt = 0; nt < NT; nt++)
          acc[mt][nt] = MFMA16(af[mt], bfr[nt], acc[mt][nt]);
    }
  }

  if (MODE == 0) {
    u16* op = (u16*)outp;
#pragma unroll
    for (int mt = 0; mt < 4; mt++) {
      int row0 = tile_m + wm * 64 + mt * 16 + quad * 4;
      int bb = row0 >> 12;
      int sbase = row0 & (S0 - 1);
#pragma unroll
      for (int nt = 0; nt < NT; nt++) {
        int col = tile_n + wn * (BN / 2) + nt * 16 + l16;
        int p = col >> 10;
        int rem = col & 1023;
        float bias = bf2f(cb[p * 1024 + rem]);
        int hh = rem >> 6, dd = rem & 63;
        u16* dp = op + ((size_t)(((p * 2 + bb) * NH + hh)) * S0 + sbase) * HD + dd;
#pragma unroll
        for (int r = 0; r < 4; r++)
          dp[(size_t)r * HD] = f2bf(acc[mt][nt][r] + bias);
      }
    }
  } else {
    float* op = (float*)outp;
#pragma unroll
    for (int mt = 0; mt < 4; mt++) {
      int row0 = tile_m + wm * 64 + mt * 16 + quad * 4;
#pragma unroll
      for (int nt = 0; nt < NT; nt++) {
        int col = tile_n + wn * (BN / 2) + nt * 16 + l16;
        float bias = bf2f(cb[3 * 1024 + col]);
        float* dp = op + (size_t)row0 * HID + col;
#pragma unroll
        for (int r = 0; r < 4; r++)
          dp[(size_t)r * HID] = acc[mt][nt][r] + bias;  // fp32 output
      }
    }
  }
}

// ---------------- windowed attention: one block per (b, h, chunk) ----------
// Wave w covers queries [w*16, w*16+16) and keys [w*16, w*16+144) rel kbase
// (exactly the band). K staged in LDS (XOR-swizzled); same buffer re-staged
// as V^T (stride VSTR -> conflict-free PV ds_read_b128); V global loads
// issued before softmax to hide latency; Q hoisted above the first barrier.
// LDS 51.6 KB -> 3 blocks/CU.
__global__ __launch_bounds__(256) void attn_win(
    const u16* __restrict__ Q, const u16* __restrict__ Kp,
    const u16* __restrict__ Vp, const u16* __restrict__ cmask,
    u16* __restrict__ ctx) {
  __shared__ alignas(16) u16 buf0[64 * VSTR];   // phase1: K swizzled [slot][64]
                                                // phase2: V^T [d][VSTR]
  __shared__ alignas(16) u16 sP[4 * 16 * PSTR]; // [wave][qrow][key 0..160)
  __shared__ u16 sMk[208];

  int bid = blockIdx.x;
  int c = bid & 63;
  int h = (bid >> 6) & 15;
  int b = bid >> 10;
  int t = threadIdx.x;
  int wave = t >> 6, lane = t & 63;
  int quad = lane >> 4, l16 = lane & 15;
  int koff = wave * 16;  // this wave's key-window start (rel kbase)

  const u16* Qb = Q + (size_t)(b * NH + h) * S0 * HD;
  const u16* Kb = Kp + (size_t)(b * NH + h) * S0 * HD;
  const u16* Vb = Vp + (size_t)(b * NH + h) * S0 * HD;
  int kbase = (c - 1) * 64;  // global key index of slot 0

  // ---- stage K via glds16, source-swizzled (chunk csrc -> LDS chunk l&7) --
  int rrow = lane >> 3;                 // row within the wave's 8-row group
  int csrc = ((lane & 7) ^ rrow) * 8;   // swizzled source chunk (elems)
#pragma unroll
  for (int p = 0; p < 7; p++) {
    int sl0 = p * 32 + wave * 8;        // wave-uniform row base (mult of 8)
    if (sl0 < 208) {
      int key = kbase + sl0 + rrow;
      int kc = key < 0 ? 0 : (key > S0 - 1 ? S0 - 1 : key);
      glds16(Kb + (size_t)kc * HD + csrc, buf0 + sl0 * 64);
    }
  }
  if (t < 208) {
    int j = kbase + t;
    sMk[t] = (j >= 0 && j < S0) ? cmask[(size_t)b * S0 + j] : (u16)0;
  }

  // ---- hoist Q fragments: global-load latency overlaps the K-stage drain --
  int qrow = c * 64 + wave * 16 + l16;
  bf16x8 aqv[2];
#pragma unroll
  for (int ks = 0; ks < 2; ks++)
    aqv[ks] = *(const bf16x8*)(Qb + (size_t)qrow * HD + ks * 32 + quad * 8);

  __syncthreads();

  // ---- QK from LDS: 9 key tiles cover the band exactly --------------------
  floatx4 sc[9] = {};
  __builtin_amdgcn_s_setprio(1);
#pragma unroll
  for (int ks = 0; ks < 2; ks++) {
#pragma unroll
    for (int nt = 0; nt < 9; nt++) {
      int slot = koff + nt * 16 + l16;
      int pch = ((ks * 4 + quad) ^ (l16 & 7)) * 8;  // un-swizzle
      bf16x8 bk = *(const bf16x8*)(buf0 + slot * 64 + pch);
      sc[nt] = MFMA16(aqv[ks], bk, sc[nt]);
    }
  }
  __builtin_amdgcn_s_setprio(0);

  // ---- preload V into registers (latency hides under softmax) -------------
  u16x8 vreg[7];
#pragma unroll
  for (int i = 0; i < 7; i++) {
    int e = i * 256 + t;  // 208*8 = 1664 tasks
    if (e < 1664) {
      int dg = e / 208;         // d block of 8
      int slot = e - dg * 208;  // 0..207
      int key = kbase + slot;
      int kc = key < 0 ? 0 : (key > S0 - 1 ? S0 - 1 : key);
      vreg[i] = *(const u16x8*)(Vb + (size_t)kc * HD + dg * 8);
    }
  }

  // ---- mask + softmax (rows across the 16 lanes of a quad) + write P ------
  int qrel_base = wave * 16 + quad * 4;
  u16* myP = sP + wave * 16 * PSTR;
  float kmask[9];
#pragma unroll
  for (int nt = 0; nt < 9; nt++) kmask[nt] = bf2f(sMk[koff + nt * 16 + l16]);

#pragma unroll
  for (int reg = 0; reg < 4; reg++) {
    int qrel = qrel_base + reg;
    float v[9];
    float m = -3e38f;
#pragma unroll
    for (int nt = 0; nt < 9; nt++) {
      int slot = koff + nt * 16 + l16;  // band: qrel <= slot <= qrel+128
      bool ok = (slot >= qrel) && (slot <= qrel + 128) && (kmask[nt] > 0.f);
      float s = ok ? sc[nt][reg] * 0.125f : -1e30f;
      v[nt] = s;
      m = fmaxf(m, s);
    }
#pragma unroll
    for (int off = 1; off <= 8; off <<= 1) m = fmaxf(m, __shfl_xor(m, off));
    float sum = 0.f;
#pragma unroll
    for (int nt = 0; nt < 9; nt++) {
      float p = __expf(v[nt] - m);
      v[nt] = p;
      sum += p;
    }
#pragma unroll
    for (int off = 1; off <= 8; off <<= 1) sum += __shfl_xor(sum, off);
    float inv = 1.0f / sum;
    int prow = (quad * 4 + reg) * PSTR;
#pragma unroll
    for (int nt = 0; nt < 9; nt++)
      myP[prow + nt * 16 + l16] = f2bf(v[nt] * inv);
    myP[prow + 144 + l16] = 0;  // zero-pad tile 9 -> P width 160
  }
  __syncthreads();  // all waves done reading K from buf0

  // ---- scatter V^T into buf0 ([d][key], stride VSTR) ----------------------
#pragma unroll
  for (int i = 0; i < 7; i++) {
    int e = i * 256 + t;
    if (e < 1664) {
      int dg = e / 208;
      int slot = e - dg * 208;
#pragma unroll
      for (int j = 0; j < 8; j++) buf0[(dg * 8 + j) * VSTR + slot] = vreg[i][j];
    }
  }
  __syncthreads();

  // ---- PV over the 160-key padded window ----------------------------------
  floatx4 oc[4] = {};
  __builtin_amdgcn_s_setprio(1);
#pragma unroll
  for (int ks = 0; ks < 5; ks++) {
    bf16x8 ap = *(const bf16x8*)(myP + l16 * PSTR + ks * 32 + quad * 8);
#pragma unroll
    for (int nt = 0; nt < 4; nt++) {
      bf16x8 bv =
          *(const bf16x8*)(buf0 + (nt * 16 + l16) * VSTR + koff + ks * 32 + quad * 8);
      oc[nt] = MFMA16(ap, bv, oc[nt]);
    }
  }
  __builtin_amdgcn_s_setprio(0);

  int srow = c * 64 + wave * 16 + quad * 4;
#pragma unroll
  for (int nt = 0; nt < 4; nt++) {
    u16* dp = ctx + (size_t)(b * S0 + srow) * HID + h * HD + nt * 16 + l16;
#pragma unroll
    for (int reg = 0; reg < 4; reg++)
      dp[(size_t)reg * HID] = f2bf(oc[nt][reg]);
  }
}

// ---------------------------------------------------------------------------
extern "C" void kernel_launch(void* const* d_in, const int* in_sizes, int n_in,
                              void* d_out, int out_size, void* d_ws, size_t ws_size,
                              hipStream_t stream) {
  const float* X = (const float*)d_in[0];
  const float* mask = (const float*)d_in[1];
  const float* Wq = (const float*)d_in[2];
  const float* bq = (const float*)d_in[3];
  const float* Wk = (const float*)d_in[4];
  const float* bk = (const float*)d_in[5];
  const float* Wv = (const float*)d_in[6];
  const float* bv = (const float*)d_in[7];
  const float* Wo = (const float*)d_in[8];
  const float* bo = (const float*)d_in[9];
  char* ws = (char*)d_ws;

  const size_t MB = 1048576;
  u16* cmask = (u16*)(ws + 256);               // 16 KB
  u16* cb = (u16*)(ws + 256 + 16384);          // 8 KB
  u16* cX = (u16*)(ws + 1 * MB);               // 16 MB (CTX aliases after gemm0)
  u16* WqkvT = (u16*)(ws + 17 * MB);           // 6 MB
  u16* WoT = (u16*)(ws + 23 * MB);             // 2 MB
  u16* QKV = (u16*)(ws + 25 * MB);             // 48 MB
  u16* CTX = cX;                               // alias: cX dead after gemm0

  const size_t per_qkv = (size_t)B_ * NH * S0 * HD;  // elements per Q/K/V

  prep<<<4096 + 48 + 1024, 256, 0, stream>>>(X, mask, Wq, bq, Wk, bk, Wv, bv,
                                             Wo, bo, cX, cmask, cb, WqkvT, WoT);
  // n-major grids: x = N-tiles, y = M-tiles
  gemm_bf16_tn<96, 0><<<dim3(32, 64), 256, 0, stream>>>(cX, WqkvT, cb, QKV, HID);
  attn_win<<<dim3(B_ * NH * 64), 256, 0, stream>>>(QKV, QKV + per_qkv,
                                                   QKV + 2 * per_qkv, cmask, CTX);
  gemm_bf16_tn<128, 1><<<dim3(8, 64), 256, 0, stream>>>(CTX, WoT, cb, d_out, HID);
}